// Round 10
// baseline (428.327 us; speedup 1.0000x reference)
//
#include <hip/hip_runtime.h>

// EdgeNet: BN -> inputnet MLP -> EdgeConv(linearized) -> mean-pool -> output MLP
// N=50000, E=1.6M, D=13, H=32, G=128. All I/O float32.
// EdgeConv: per-node A = feat@(Wtop-Wbot)+b1, B = feat@Wbot (fp16);
// per-edge h = relu(A[dst]+B[src]); msg = tanh(h@W2+b2) via MFMA f16.
// R16 (260.6us): node split (nodeA MLP + nodeB dense MFMA GEMM), pool TLP.
// R17: ELIMINATE Hn. Key insight: Hn is only consumed by the per-graph pool,
//   so msg can be accumulated directly into gacc[g][c] (g=batch[dst]):
//   - k_edgeg: per-block LDS f32 acc [128][32] (16KB), ds_add_f32 per edge
//     channel pair, one staggered f32-atomic flush (4096/block) at end.
//   - removes: 25.6M global RMW atomics (the measured 288G/s ~ TCC-slot
//     ceiling that made R11 scheduling invariant), 100MB Hn write stream,
//     Hn buffer + zeroing, and the entire k_pool launch (6 -> 5 launches).
//   - accumulation f16 -> f32 (absmax should improve).
//   Grid 2048 blocks (8/CU x 16KB = 128KB LDS, same 32 waves/CU as R9).

typedef __attribute__((ext_vector_type(4))) float floatx4;
typedef __attribute__((ext_vector_type(8))) short short8;
typedef __attribute__((ext_vector_type(8))) _Float16 half8;
typedef __attribute__((ext_vector_type(2))) __fp16 fp16x2;

__device__ __forceinline__ unsigned short f2bf(float f) {
    unsigned int u = __float_as_uint(f);
    u += 0x7FFFu + ((u >> 16) & 1u);   // RTNE
    return (unsigned short)(u >> 16);
}
__device__ __forceinline__ unsigned short f2h(float f) {
    _Float16 h = (_Float16)f;
    return __builtin_bit_cast(unsigned short, h);
}
__device__ __forceinline__ float h2f(unsigned short u) {
    return (float)__builtin_bit_cast(_Float16, u);
}
__device__ __forceinline__ float fast_tanh(float x) {
    float ax = fminf(fabsf(x), 20.0f);
    float e = __expf(2.0f * ax);
    float r = 1.0f - 2.0f * __builtin_amdgcn_rcpf(e + 1.0f);
    return copysignf(r, x);
}
__device__ __forceinline__ float fast_sigmoid(float x) {
    float xc = fminf(fmaxf(x, -30.f), 30.f);
    return 1.0f / (1.0f + __expf(-xc));
}

#define NBLK_STAT 120
#define GMAX 128   // G for this problem (batch values < 128)

// ---- K1: BN partials + zero gacc + precompute WcatT (bf16 [128][64]) ----
__global__ __launch_bounds__(256) void k_bnstat(const float* __restrict__ x, int N,
                                                float* __restrict__ part,
                                                float* __restrict__ gacc, int gn,
                                                const float* __restrict__ conv_w1,
                                                unsigned short* __restrict__ wcat) {
    int tid = blockIdx.x * blockDim.x + threadIdx.x;
    int stride = gridDim.x * blockDim.x;
    for (int i = tid; i < gn; i += stride) gacc[i] = 0.f;
    // WcatT[c][k], c=0..127 output col, k=0..63 input: top-bot | bot
    for (int i = tid; i < 128 * 64; i += stride) {
        int c = i >> 6, k = i & 63;
        float v = 0.f;
        if (k < 45) {
            int cc = c & 63;
            float bot = conv_w1[(45 + k) * 64 + cc];
            v = (c < 64) ? (conv_w1[k * 64 + cc] - bot) : bot;
        }
        wcat[i] = f2bf(v);
    }

    float s[13], q[13];
#pragma unroll
    for (int d = 0; d < 13; d++) { s[d] = 0.f; q[d] = 0.f; }
    for (int n = tid; n < N; n += stride) {
        const float* row = x + (size_t)n * 13;
#pragma unroll
        for (int d = 0; d < 13; d++) { float f = row[d]; s[d] += f; q[d] += f * f; }
    }
#pragma unroll
    for (int d = 0; d < 13; d++) {
        for (int off = 32; off > 0; off >>= 1) {
            s[d] += __shfl_down(s[d], off, 64);
            q[d] += __shfl_down(q[d], off, 64);
        }
    }
    __shared__ float red[4][26];
    int w = threadIdx.x >> 6;
    if ((threadIdx.x & 63) == 0) {
#pragma unroll
        for (int d = 0; d < 13; d++) { red[w][d] = s[d]; red[w][13 + d] = q[d]; }
    }
    __syncthreads();
    if (threadIdx.x < 26) {
        float v = red[0][threadIdx.x] + red[1][threadIdx.x] + red[2][threadIdx.x] + red[3][threadIdx.x];
        int d = threadIdx.x;
        if (d < 13) part[blockIdx.x * 32 + d] = v;
        else        part[NBLK_STAT * 32 + blockIdx.x * 32 + (d - 13)] = v;
    }
}

// ---------------- K2a: per-node MLP -> feat (bf16 [Npad][64]) ----------------
__global__ __launch_bounds__(256) void k_nodeA(
    const float* __restrict__ x, const int* __restrict__ batch,
    const float* __restrict__ bn_g, const float* __restrict__ bn_b,
    const float* __restrict__ in_w1, const float* __restrict__ in_b1,
    const float* __restrict__ in_w2, const float* __restrict__ in_b2,
    const float* __restrict__ part,
    unsigned short* __restrict__ feat, float* __restrict__ gacc, int N) {
    __shared__ float sW1[13 * 32], sB1[32], sW2[32 * 32], sB2[32];
    __shared__ float sScl[16], sShf[16];
    __shared__ float sRedS[13][8], sRedQ[13][8];
    __shared__ unsigned short sFeat[256 * 64];
    int tid = threadIdx.x;

    for (int i = tid; i < 13 * 32; i += 256) sW1[i] = in_w1[i];
    if (tid < 32) { sB1[tid] = in_b1[tid]; sB2[tid] = in_b2[tid]; }
    for (int i = tid; i < 32 * 32; i += 256) sW2[i] = in_w2[i];
    if (tid < 104) {
        int d = tid >> 3, j = tid & 7;
        float su = 0.f, sq = 0.f;
        for (int b = j; b < NBLK_STAT; b += 8) {
            su += part[b * 32 + d];
            sq += part[NBLK_STAT * 32 + b * 32 + d];
        }
        sRedS[d][j] = su; sRedQ[d][j] = sq;
    }
    __syncthreads();
    if (tid < 13) {
        float su = 0.f, sq = 0.f;
#pragma unroll
        for (int j = 0; j < 8; j++) { su += sRedS[tid][j]; sq += sRedQ[tid][j]; }
        float invN = 1.0f / (float)N;
        float mu = su * invN;
        float var = fmaxf(sq * invN - mu * mu, 0.f);
        float sc = bn_g[tid] / sqrtf(var + 1e-5f);
        sScl[tid] = sc;
        sShf[tid] = bn_b[tid] - mu * sc;
    }
    __syncthreads();

    int n = blockIdx.x * 256 + tid;
    bool valid = (n < N);
    int nl = valid ? n : (N - 1);

    float X[13];
#pragma unroll
    for (int d = 0; d < 13; d++)
        X[d] = x[(size_t)nl * 13 + d] * sScl[d] + sShf[d];
    float h1[32];
#pragma unroll
    for (int j = 0; j < 32; j++) {
        float acc = sB1[j];
#pragma unroll
        for (int d = 0; d < 13; d++) acc += X[d] * sW1[d * 32 + j];
        h1[j] = fmaxf(acc, 0.f);
    }
    float h2[32];
#pragma unroll
    for (int j = 0; j < 32; j++) {
        float acc = sB2[j];
#pragma unroll
        for (int k = 0; k < 32; k++) acc += h1[k] * sW2[k * 32 + j];
        h2[j] = fast_tanh(acc);
    }

    unsigned int fw[16];
#pragma unroll
    for (int i = 0; i < 16; i++) fw[i] = 0;
    unsigned int xw[7];
#pragma unroll
    for (int i = 0; i < 7; i++) xw[i] = 0;
    if (valid) {
#pragma unroll
        for (int i = 0; i < 16; i++)
            fw[i] = (unsigned)f2bf(h2[2 * i]) | ((unsigned)f2bf(h2[2 * i + 1]) << 16);
#pragma unroll
        for (int i = 0; i < 6; i++)
            xw[i] = (unsigned)f2bf(X[2 * i]) | ((unsigned)f2bf(X[2 * i + 1]) << 16);
        xw[6] = (unsigned)f2bf(X[12]);
    }
    {
        unsigned short* row = sFeat + tid * 64;
        ((uint4*)row)[0] = make_uint4(fw[0], fw[1], fw[2], fw[3]);
        ((uint4*)row)[1] = make_uint4(fw[4], fw[5], fw[6], fw[7]);
        ((uint4*)row)[2] = make_uint4(fw[8], fw[9], fw[10], fw[11]);
        ((uint4*)row)[3] = make_uint4(fw[12], fw[13], fw[14], fw[15]);
        ((uint4*)row)[4] = make_uint4(xw[0], xw[1], xw[2], xw[3]);
        ((uint4*)row)[5] = make_uint4(xw[4], xw[5], xw[6], 0u);
        ((uint4*)row)[6] = make_uint4(0u, 0u, 0u, 0u);
        ((uint4*)row)[7] = make_uint4(0u, 0u, 0u, 0u);
    }

    {
        int g = valid ? batch[n] : -1;
        unsigned long long uni = __ballot(g == __shfl(g, 0, 64));
        if (uni == ~0ull && g >= 0) {
            float red[14];
#pragma unroll
            for (int d = 0; d < 13; d++) red[d] = X[d];
            red[13] = 1.0f;
#pragma unroll
            for (int d = 0; d < 14; d++)
                for (int off = 32; off > 0; off >>= 1)
                    red[d] += __shfl_down(red[d], off, 64);
            if ((tid & 63) == 0) {
#pragma unroll
                for (int d = 0; d < 13; d++) unsafeAtomicAdd(&gacc[g * 46 + 32 + d], red[d]);
                unsafeAtomicAdd(&gacc[g * 46 + 45], red[13]);
            }
        } else if (valid) {
#pragma unroll
            for (int d = 0; d < 13; d++) unsafeAtomicAdd(&gacc[g * 46 + 32 + d], X[d]);
            unsafeAtomicAdd(&gacc[g * 46 + 45], 1.0f);
        }
    }
    __syncthreads();

    // coalesced linear copy: 256*64 ushorts = 2048 uint4
    uint4* dst = (uint4*)(feat + (size_t)blockIdx.x * 256 * 64);
    const uint4* srcq = (const uint4*)sFeat;
#pragma unroll
    for (int j = 0; j < 8; j++) dst[tid + j * 256] = srcq[tid + j * 256];
}

// ---------------- K2b: dense GEMM feat@WcatT -> A|Bm (fp16) ----------------
__global__ __launch_bounds__(256) void k_nodeB(
    const unsigned short* __restrict__ feat, const unsigned short* __restrict__ wcat,
    const float* __restrict__ conv_b1,
    unsigned short* __restrict__ A, unsigned short* __restrict__ Bm, int N) {
    int tid = threadIdx.x;
    int lane = tid & 63;
    int w = tid >> 6;
    int q = lane >> 4;
    int m = lane & 15;

    short8 wf[2][8];
#pragma unroll
    for (int ks = 0; ks < 2; ks++)
#pragma unroll
        for (int t = 0; t < 8; t++)
            wf[ks][t] = *(const short8*)(wcat + (t * 16 + m) * 64 + ks * 32 + q * 8);
    float cb1v[4];
#pragma unroll
    for (int t = 0; t < 4; t++) cb1v[t] = conv_b1[t * 16 + m];

    int row0 = blockIdx.x * 64 + w * 16;
    const unsigned short* ar = feat + (size_t)(row0 + m) * 64;
    short8 a0 = *(const short8*)(ar + q * 8);
    short8 a1 = *(const short8*)(ar + 32 + q * 8);
    floatx4 c[8];
#pragma unroll
    for (int t = 0; t < 8; t++) {
        floatx4 z = {0.f, 0.f, 0.f, 0.f};
        c[t] = __builtin_amdgcn_mfma_f32_16x16x32_bf16(a0, wf[0][t], z, 0, 0, 0);
        c[t] = __builtin_amdgcn_mfma_f32_16x16x32_bf16(a1, wf[1][t], c[t], 0, 0, 0);
    }
#pragma unroll
    for (int r = 0; r < 4; r++) {
        int row = row0 + (q << 2) + r;
        if (row < N) {
#pragma unroll
            for (int t = 0; t < 4; t++)
                A[(size_t)row * 64 + t * 16 + m] = f2h(c[t][r] + cb1v[t]);
#pragma unroll
            for (int t = 4; t < 8; t++)
                Bm[(size_t)row * 64 + (t - 4) * 16 + m] = f2h(c[t][r]);
        }
    }
}

// ---------------- K3: edge phase, LDS-graph accumulation (no Hn) -----------
__global__ __launch_bounds__(256) void k_edgeg(
    const int* __restrict__ ei,
    const unsigned short* __restrict__ A, const unsigned short* __restrict__ Bm,
    const float* __restrict__ conv_w2, const float* __restrict__ conv_b2,
    const int* __restrict__ batch,
    float* __restrict__ gacc, int E) {
    __shared__ float sAcc[GMAX][32];
    int tid = threadIdx.x;
    for (int i = tid; i < GMAX * 32; i += 256) ((float*)sAcc)[i] = 0.f;

    int lane = tid & 63;
    int wid  = blockIdx.x * (blockDim.x >> 6) + (tid >> 6);
    int nw   = gridDim.x * (blockDim.x >> 6);
    int q = lane >> 4;
    int m = lane & 15;

    half8 wf[2][2];
#pragma unroll
    for (int s = 0; s < 2; s++)
#pragma unroll
        for (int t = 0; t < 2; t++)
#pragma unroll
            for (int j = 0; j < 8; j++)
                wf[s][t][j] = (_Float16)conv_w2[(s * 32 + q * 8 + j) * 32 + 2 * m + t];
    float cb2a = conv_b2[2 * m];
    float cb2b = conv_b2[2 * m + 1];

    const int* srcp = ei;
    const int* dstp = ei + E;
    int npairs = E >> 5;

    const half8 zero8 = (half8)(_Float16)0.0f;

    __syncthreads();

    for (int p = wid; p < npairs; p += nw) {
        int e0 = p << 5;
        int vd0 = dstp[e0 + m];
        int vs0 = srcp[e0 + m];
        int vd1 = dstp[e0 + 16 + m];
        int vs1 = srcp[e0 + 16 + m];
        int gd0 = batch[vd0];
        int gd1 = batch[vd1];
        uint4 av0a = *(const uint4*)(A  + (size_t)vd0 * 64 + q * 8);
        uint4 av0b = *(const uint4*)(A  + (size_t)vd0 * 64 + 32 + q * 8);
        uint4 bv0a = *(const uint4*)(Bm + (size_t)vs0 * 64 + q * 8);
        uint4 bv0b = *(const uint4*)(Bm + (size_t)vs0 * 64 + 32 + q * 8);
        uint4 av1a = *(const uint4*)(A  + (size_t)vd1 * 64 + q * 8);
        uint4 av1b = *(const uint4*)(A  + (size_t)vd1 * 64 + 32 + q * 8);
        uint4 bv1a = *(const uint4*)(Bm + (size_t)vs1 * 64 + q * 8);
        uint4 bv1b = *(const uint4*)(Bm + (size_t)vs1 * 64 + 32 + q * 8);

        auto mk = [&zero8](uint4 av, uint4 bv) -> half8 {
            half8 a = __builtin_bit_cast(half8, av);
            half8 b = __builtin_bit_cast(half8, bv);
            half8 s = a + b;
            return __builtin_elementwise_max(s, zero8);
        };
        half8 h0a = mk(av0a, bv0a);
        half8 h0b = mk(av0b, bv0b);
        half8 h1a = mk(av1a, bv1a);
        half8 h1b = mk(av1b, bv1b);

        floatx4 c00 = {0.f, 0.f, 0.f, 0.f}, c01 = {0.f, 0.f, 0.f, 0.f};
        floatx4 c10 = {0.f, 0.f, 0.f, 0.f}, c11 = {0.f, 0.f, 0.f, 0.f};
        c00 = __builtin_amdgcn_mfma_f32_16x16x32_f16(h0a, wf[0][0], c00, 0, 0, 0);
        c01 = __builtin_amdgcn_mfma_f32_16x16x32_f16(h0a, wf[0][1], c01, 0, 0, 0);
        c10 = __builtin_amdgcn_mfma_f32_16x16x32_f16(h1a, wf[0][0], c10, 0, 0, 0);
        c11 = __builtin_amdgcn_mfma_f32_16x16x32_f16(h1a, wf[0][1], c11, 0, 0, 0);
        c00 = __builtin_amdgcn_mfma_f32_16x16x32_f16(h0b, wf[1][0], c00, 0, 0, 0);
        c01 = __builtin_amdgcn_mfma_f32_16x16x32_f16(h0b, wf[1][1], c01, 0, 0, 0);
        c10 = __builtin_amdgcn_mfma_f32_16x16x32_f16(h1b, wf[1][0], c10, 0, 0, 0);
        c11 = __builtin_amdgcn_mfma_f32_16x16x32_f16(h1b, wf[1][1], c11, 0, 0, 0);

#pragma unroll
        for (int r = 0; r < 4; r++) {
            int m2 = (q << 2) + r;
            int gg0 = __shfl(gd0, m2, 64);
            int gg1 = __shfl(gd1, m2, 64);
            float o00 = fast_tanh(c00[r] + cb2a);
            float o01 = fast_tanh(c01[r] + cb2b);
            float o10 = fast_tanh(c10[r] + cb2a);
            float o11 = fast_tanh(c11[r] + cb2b);
            atomicAdd(&sAcc[gg0][2 * m], o00);
            atomicAdd(&sAcc[gg0][2 * m + 1], o01);
            atomicAdd(&sAcc[gg1][2 * m], o10);
            atomicAdd(&sAcc[gg1][2 * m + 1], o11);
        }
    }

    // tail: edges beyond the last full 32-pair (covers E%32; E=1.6M -> empty)
    int tstart = npairs << 5;
    int tail = E - tstart;
    if (tail && blockIdx.x == 0 && tid < tail) {
        int e = tstart + tid;
        int vd = dstp[e], vs = srcp[e];
        int g = batch[vd];
        float h[64];
        for (int k = 0; k < 64; k++) {
            float a = h2f(A[(size_t)vd * 64 + k]);
            float b = h2f(Bm[(size_t)vs * 64 + k]);
            h[k] = fmaxf(a + b, 0.f);
        }
        for (int j = 0; j < 32; j++) {
            float acc = conv_b2[j];
            for (int k = 0; k < 64; k++) acc += h[k] * conv_w2[k * 32 + j];
            atomicAdd(&sAcc[g][j], fast_tanh(acc));
        }
    }

    __syncthreads();
    // staggered flush: 4096 f32 atomics per block into gacc
    for (int i = tid; i < GMAX * 32; i += 256) {
        int g = i >> 5, c = i & 31;
        float v = sAcc[g][c];
        if (v != 0.f) unsafeAtomicAdd(&gacc[g * 46 + c], v);
    }
}

// ---------------- K5: output MLP ----------------
__global__ void k_out(const float* __restrict__ gacc,
                      const float* __restrict__ out_w1, const float* __restrict__ out_b1,
                      const float* __restrict__ out_w2, const float* __restrict__ out_b2,
                      float* __restrict__ out, int G) {
    int g = blockIdx.x * blockDim.x + threadIdx.x;
    if (g >= G) return;
    float cnt = fmaxf(gacc[g * 46 + 45], 1.0f);
    float inv = 1.0f / cnt;
    float f[45];
#pragma unroll
    for (int i = 0; i < 45; i++) f[i] = gacc[g * 46 + i] * inv;
    float h[32];
#pragma unroll
    for (int j = 0; j < 32; j++) {
        float acc = out_b1[j];
#pragma unroll
        for (int k = 0; k < 45; k++) acc += f[k] * out_w1[k * 32 + j];
        h[j] = fmaxf(acc, 0.f);
    }
    float o = out_b2[0];
#pragma unroll
    for (int j = 0; j < 32; j++) o += h[j] * out_w2[j];
    out[g] = fast_sigmoid(o);
}

extern "C" void kernel_launch(void* const* d_in, const int* in_sizes, int n_in,
                              void* d_out, int out_size, void* d_ws, size_t ws_size,
                              hipStream_t stream) {
    const float* x      = (const float*)d_in[0];
    const int*   ei     = (const int*)d_in[1];
    const int*   batch  = (const int*)d_in[2];
    const float* bn_g   = (const float*)d_in[3];
    const float* bn_b   = (const float*)d_in[4];
    const float* in_w1  = (const float*)d_in[5];
    const float* in_b1  = (const float*)d_in[6];
    const float* in_w2  = (const float*)d_in[7];
    const float* in_b2  = (const float*)d_in[8];
    const float* cw1    = (const float*)d_in[9];
    const float* cb1    = (const float*)d_in[10];
    const float* cw2    = (const float*)d_in[11];
    const float* cb2    = (const float*)d_in[12];
    const float* ow1    = (const float*)d_in[13];
    const float* ob1    = (const float*)d_in[14];
    const float* ow2    = (const float*)d_in[15];
    const float* ob2    = (const float*)d_in[16];

    int N = in_sizes[0] / 13;
    int E = in_sizes[1] / 2;
    int G = out_size;
    int Npad = (N + 255) & ~255;

    auto al = [](size_t v) { return (v + 255) & ~(size_t)255; };
    char* ws = (char*)d_ws;
    size_t gacc_off = 0;
    size_t part_off = gacc_off + al((size_t)G * 46 * 4);
    size_t a_off    = part_off + al(2 * NBLK_STAT * 32 * 4);
    size_t b_off    = a_off + al((size_t)Npad * 64 * 2);
    size_t ft_off   = b_off + al((size_t)Npad * 64 * 2);
    size_t wc_off   = ft_off + al((size_t)Npad * 64 * 2);

    float* gacc          = (float*)(ws + gacc_off);
    float* part          = (float*)(ws + part_off);
    unsigned short* A    = (unsigned short*)(ws + a_off);
    unsigned short* Bm   = (unsigned short*)(ws + b_off);
    unsigned short* feat = (unsigned short*)(ws + ft_off);
    unsigned short* wcat = (unsigned short*)(ws + wc_off);

    int gn = G * 46;

    k_bnstat<<<NBLK_STAT, 256, 0, stream>>>(x, N, part, gacc, gn, cw1, wcat);
    k_nodeA<<<Npad / 256, 256, 0, stream>>>(x, batch, bn_g, bn_b,
                                            in_w1, in_b1, in_w2, in_b2,
                                            part, feat, gacc, N);
    k_nodeB<<<Npad / 64, 256, 0, stream>>>(feat, wcat, cb1, A, Bm, N);
    k_edgeg<<<2048, 256, 0, stream>>>(ei, A, Bm, cw2, cb2, batch, gacc, E);
    k_out<<<1, 128, 0, stream>>>(gacc, ow1, ob1, ow2, ob2, (float*)d_out, G);
}

// Round 12
// 273.574 us; speedup vs baseline: 1.5657x; 1.5657x over previous
//
#include <hip/hip_runtime.h>

// EdgeNet: BN -> inputnet MLP -> EdgeConv(linearized) -> mean-pool -> output MLP
// N=50000, E=1.6M, D=13, H=32, G=128. All I/O float32.
// EdgeConv: per-node A = feat@(Wtop-Wbot)+b1, B = feat@Wbot (fp16);
// per-edge h = relu(A[dst]+B[src]); msg = tanh(h@W2+b2) via MFMA f16,
// scattered to Hn via packed f16 atomics.
// R16 (260.6us, BEST): node split (nodeA MLP + nodeB MFMA GEMM), pool TLP.
// R17 (LDS-graph acc): 275us edge - ds-atomic serialization. REVERTED.
// R18: NON-TEMPORAL loads for streaming reads in k_edge (indices, A/B gathers)
// + k_pool Hn reads -> keep dirty Hn lines L2-resident, atomics become
// L2-side RMW. Predict: WRITE 100MB -> <10MB, k_edge 89 -> 60-75us; if
// unchanged -> memory-side atomic roofline confirmed.
// R18b: fix builtin type (use ext_vector uintx4, not HIP_vector_type uint4).

typedef __attribute__((ext_vector_type(4))) float floatx4;
typedef __attribute__((ext_vector_type(8))) short short8;
typedef __attribute__((ext_vector_type(8))) _Float16 half8;
typedef __attribute__((ext_vector_type(2))) __fp16 fp16x2;
typedef __attribute__((ext_vector_type(4))) unsigned int uintx4;

__device__ __forceinline__ unsigned short f2bf(float f) {
    unsigned int u = __float_as_uint(f);
    u += 0x7FFFu + ((u >> 16) & 1u);   // RTNE
    return (unsigned short)(u >> 16);
}
__device__ __forceinline__ unsigned short f2h(float f) {
    _Float16 h = (_Float16)f;
    return __builtin_bit_cast(unsigned short, h);
}
__device__ __forceinline__ float h2f(unsigned short u) {
    return (float)__builtin_bit_cast(_Float16, u);
}
__device__ __forceinline__ float fast_tanh(float x) {
    float ax = fminf(fabsf(x), 20.0f);
    float e = __expf(2.0f * ax);
    float r = 1.0f - 2.0f * __builtin_amdgcn_rcpf(e + 1.0f);
    return copysignf(r, x);
}
__device__ __forceinline__ float fast_sigmoid(float x) {
    float xc = fminf(fmaxf(x, -30.f), 30.f);
    return 1.0f / (1.0f + __expf(-xc));
}
__device__ __forceinline__ unsigned int pk_h2(float a, float b) {
    fp16x2 p = __builtin_amdgcn_cvt_pkrtz(a, b);
    return __builtin_bit_cast(unsigned int, p);
}
// fire-and-forget packed f16x2 atomic add
__device__ __forceinline__ void atomic_pk_add_f16(unsigned short* addr, unsigned int packed) {
    asm volatile("global_atomic_pk_add_f16 %0, %1, off" :: "v"(addr), "v"(packed) : "memory");
}
// non-temporal 16B load of fp16x8 data
__device__ __forceinline__ half8 nt_load_h8(const unsigned short* p) {
    uintx4 v = __builtin_nontemporal_load((const uintx4*)p);
    return __builtin_bit_cast(half8, v);
}

#define NBLK_STAT 120

// ---- K1: BN partials + zero Hn/gacc + precompute WcatT (bf16 [128][64]) ----
__global__ __launch_bounds__(256) void k_bnstat(const float* __restrict__ x, int N,
                                                float* __restrict__ part,
                                                uint4* __restrict__ HnZ, int hnq,
                                                float* __restrict__ gacc, int gn,
                                                const float* __restrict__ conv_w1,
                                                unsigned short* __restrict__ wcat) {
    int tid = blockIdx.x * blockDim.x + threadIdx.x;
    int stride = gridDim.x * blockDim.x;
    uint4 z4 = make_uint4(0u, 0u, 0u, 0u);
    for (int i = tid; i < hnq; i += stride) HnZ[i] = z4;
    for (int i = tid; i < gn; i += stride) gacc[i] = 0.f;
    // WcatT[c][k], c=0..127 output col, k=0..63 input: top-bot | bot
    for (int i = tid; i < 128 * 64; i += stride) {
        int c = i >> 6, k = i & 63;
        float v = 0.f;
        if (k < 45) {
            int cc = c & 63;
            float bot = conv_w1[(45 + k) * 64 + cc];
            v = (c < 64) ? (conv_w1[k * 64 + cc] - bot) : bot;
        }
        wcat[i] = f2bf(v);
    }

    float s[13], q[13];
#pragma unroll
    for (int d = 0; d < 13; d++) { s[d] = 0.f; q[d] = 0.f; }
    for (int n = tid; n < N; n += stride) {
        const float* row = x + (size_t)n * 13;
#pragma unroll
        for (int d = 0; d < 13; d++) { float f = row[d]; s[d] += f; q[d] += f * f; }
    }
#pragma unroll
    for (int d = 0; d < 13; d++) {
        for (int off = 32; off > 0; off >>= 1) {
            s[d] += __shfl_down(s[d], off, 64);
            q[d] += __shfl_down(q[d], off, 64);
        }
    }
    __shared__ float red[4][26];
    int w = threadIdx.x >> 6;
    if ((threadIdx.x & 63) == 0) {
#pragma unroll
        for (int d = 0; d < 13; d++) { red[w][d] = s[d]; red[w][13 + d] = q[d]; }
    }
    __syncthreads();
    if (threadIdx.x < 26) {
        float v = red[0][threadIdx.x] + red[1][threadIdx.x] + red[2][threadIdx.x] + red[3][threadIdx.x];
        int d = threadIdx.x;
        if (d < 13) part[blockIdx.x * 32 + d] = v;
        else        part[NBLK_STAT * 32 + blockIdx.x * 32 + (d - 13)] = v;
    }
}

// ---------------- K2a: per-node MLP -> feat (bf16 [Npad][64]) ----------------
__global__ __launch_bounds__(256) void k_nodeA(
    const float* __restrict__ x, const int* __restrict__ batch,
    const float* __restrict__ bn_g, const float* __restrict__ bn_b,
    const float* __restrict__ in_w1, const float* __restrict__ in_b1,
    const float* __restrict__ in_w2, const float* __restrict__ in_b2,
    const float* __restrict__ part,
    unsigned short* __restrict__ feat, float* __restrict__ gacc, int N) {
    __shared__ float sW1[13 * 32], sB1[32], sW2[32 * 32], sB2[32];
    __shared__ float sScl[16], sShf[16];
    __shared__ float sRedS[13][8], sRedQ[13][8];
    __shared__ unsigned short sFeat[256 * 64];
    int tid = threadIdx.x;

    for (int i = tid; i < 13 * 32; i += 256) sW1[i] = in_w1[i];
    if (tid < 32) { sB1[tid] = in_b1[tid]; sB2[tid] = in_b2[tid]; }
    for (int i = tid; i < 32 * 32; i += 256) sW2[i] = in_w2[i];
    if (tid < 104) {
        int d = tid >> 3, j = tid & 7;
        float su = 0.f, sq = 0.f;
        for (int b = j; b < NBLK_STAT; b += 8) {
            su += part[b * 32 + d];
            sq += part[NBLK_STAT * 32 + b * 32 + d];
        }
        sRedS[d][j] = su; sRedQ[d][j] = sq;
    }
    __syncthreads();
    if (tid < 13) {
        float su = 0.f, sq = 0.f;
#pragma unroll
        for (int j = 0; j < 8; j++) { su += sRedS[tid][j]; sq += sRedQ[tid][j]; }
        float invN = 1.0f / (float)N;
        float mu = su * invN;
        float var = fmaxf(sq * invN - mu * mu, 0.f);
        float sc = bn_g[tid] / sqrtf(var + 1e-5f);
        sScl[tid] = sc;
        sShf[tid] = bn_b[tid] - mu * sc;
    }
    __syncthreads();

    int n = blockIdx.x * 256 + tid;
    bool valid = (n < N);
    int nl = valid ? n : (N - 1);

    float X[13];
#pragma unroll
    for (int d = 0; d < 13; d++)
        X[d] = x[(size_t)nl * 13 + d] * sScl[d] + sShf[d];
    float h1[32];
#pragma unroll
    for (int j = 0; j < 32; j++) {
        float acc = sB1[j];
#pragma unroll
        for (int d = 0; d < 13; d++) acc += X[d] * sW1[d * 32 + j];
        h1[j] = fmaxf(acc, 0.f);
    }
    float h2[32];
#pragma unroll
    for (int j = 0; j < 32; j++) {
        float acc = sB2[j];
#pragma unroll
        for (int k = 0; k < 32; k++) acc += h1[k] * sW2[k * 32 + j];
        h2[j] = fast_tanh(acc);
    }

    unsigned int fw[16];
#pragma unroll
    for (int i = 0; i < 16; i++) fw[i] = 0;
    unsigned int xw[7];
#pragma unroll
    for (int i = 0; i < 7; i++) xw[i] = 0;
    if (valid) {
#pragma unroll
        for (int i = 0; i < 16; i++)
            fw[i] = (unsigned)f2bf(h2[2 * i]) | ((unsigned)f2bf(h2[2 * i + 1]) << 16);
#pragma unroll
        for (int i = 0; i < 6; i++)
            xw[i] = (unsigned)f2bf(X[2 * i]) | ((unsigned)f2bf(X[2 * i + 1]) << 16);
        xw[6] = (unsigned)f2bf(X[12]);
    }
    {
        unsigned short* row = sFeat + tid * 64;
        ((uint4*)row)[0] = make_uint4(fw[0], fw[1], fw[2], fw[3]);
        ((uint4*)row)[1] = make_uint4(fw[4], fw[5], fw[6], fw[7]);
        ((uint4*)row)[2] = make_uint4(fw[8], fw[9], fw[10], fw[11]);
        ((uint4*)row)[3] = make_uint4(fw[12], fw[13], fw[14], fw[15]);
        ((uint4*)row)[4] = make_uint4(xw[0], xw[1], xw[2], xw[3]);
        ((uint4*)row)[5] = make_uint4(xw[4], xw[5], xw[6], 0u);
        ((uint4*)row)[6] = make_uint4(0u, 0u, 0u, 0u);
        ((uint4*)row)[7] = make_uint4(0u, 0u, 0u, 0u);
    }

    {
        int g = valid ? batch[n] : -1;
        unsigned long long uni = __ballot(g == __shfl(g, 0, 64));
        if (uni == ~0ull && g >= 0) {
            float red[14];
#pragma unroll
            for (int d = 0; d < 13; d++) red[d] = X[d];
            red[13] = 1.0f;
#pragma unroll
            for (int d = 0; d < 14; d++)
                for (int off = 32; off > 0; off >>= 1)
                    red[d] += __shfl_down(red[d], off, 64);
            if ((tid & 63) == 0) {
#pragma unroll
                for (int d = 0; d < 13; d++) unsafeAtomicAdd(&gacc[g * 46 + 32 + d], red[d]);
                unsafeAtomicAdd(&gacc[g * 46 + 45], red[13]);
            }
        } else if (valid) {
#pragma unroll
            for (int d = 0; d < 13; d++) unsafeAtomicAdd(&gacc[g * 46 + 32 + d], X[d]);
            unsafeAtomicAdd(&gacc[g * 46 + 45], 1.0f);
        }
    }
    __syncthreads();

    // coalesced linear copy: 256*64 ushorts = 2048 uint4
    uint4* dst = (uint4*)(feat + (size_t)blockIdx.x * 256 * 64);
    const uint4* srcq = (const uint4*)sFeat;
#pragma unroll
    for (int j = 0; j < 8; j++) dst[tid + j * 256] = srcq[tid + j * 256];
}

// ---------------- K2b: dense GEMM feat@WcatT -> A|Bm (fp16) ----------------
__global__ __launch_bounds__(256) void k_nodeB(
    const unsigned short* __restrict__ feat, const unsigned short* __restrict__ wcat,
    const float* __restrict__ conv_b1,
    unsigned short* __restrict__ A, unsigned short* __restrict__ Bm, int N) {
    int tid = threadIdx.x;
    int lane = tid & 63;
    int w = tid >> 6;
    int q = lane >> 4;
    int m = lane & 15;

    short8 wf[2][8];
#pragma unroll
    for (int ks = 0; ks < 2; ks++)
#pragma unroll
        for (int t = 0; t < 8; t++)
            wf[ks][t] = *(const short8*)(wcat + (t * 16 + m) * 64 + ks * 32 + q * 8);
    float cb1v[4];
#pragma unroll
    for (int t = 0; t < 4; t++) cb1v[t] = conv_b1[t * 16 + m];

    int row0 = blockIdx.x * 64 + w * 16;
    const unsigned short* ar = feat + (size_t)(row0 + m) * 64;
    short8 a0 = *(const short8*)(ar + q * 8);
    short8 a1 = *(const short8*)(ar + 32 + q * 8);
    floatx4 c[8];
#pragma unroll
    for (int t = 0; t < 8; t++) {
        floatx4 z = {0.f, 0.f, 0.f, 0.f};
        c[t] = __builtin_amdgcn_mfma_f32_16x16x32_bf16(a0, wf[0][t], z, 0, 0, 0);
        c[t] = __builtin_amdgcn_mfma_f32_16x16x32_bf16(a1, wf[1][t], c[t], 0, 0, 0);
    }
#pragma unroll
    for (int r = 0; r < 4; r++) {
        int row = row0 + (q << 2) + r;
        if (row < N) {
#pragma unroll
            for (int t = 0; t < 4; t++)
                A[(size_t)row * 64 + t * 16 + m] = f2h(c[t][r] + cb1v[t]);
#pragma unroll
            for (int t = 4; t < 8; t++)
                Bm[(size_t)row * 64 + (t - 4) * 16 + m] = f2h(c[t][r]);
        }
    }
}

// ---------------- K3: edge phase (R9 structure + NON-TEMPORAL reads) --------
__global__ __launch_bounds__(256) void k_edge(
    const int* __restrict__ ei,
    const unsigned short* __restrict__ A, const unsigned short* __restrict__ Bm,
    const float* __restrict__ conv_w2, const float* __restrict__ conv_b2,
    unsigned short* __restrict__ Hn, int E) {
    int lane = threadIdx.x & 63;
    int wid  = blockIdx.x * (blockDim.x >> 6) + (threadIdx.x >> 6);
    int nw   = gridDim.x * (blockDim.x >> 6);
    int q = lane >> 4;
    int m = lane & 15;

    half8 wf[2][2];
#pragma unroll
    for (int s = 0; s < 2; s++)
#pragma unroll
        for (int t = 0; t < 2; t++)
#pragma unroll
            for (int j = 0; j < 8; j++)
                wf[s][t][j] = (_Float16)conv_w2[(s * 32 + q * 8 + j) * 32 + 2 * m + t];
    float cb2a = conv_b2[2 * m];
    float cb2b = conv_b2[2 * m + 1];

    const int* srcp = ei;
    const int* dstp = ei + E;
    int npairs = E >> 5;

    const half8 zero8 = (half8)(_Float16)0.0f;

    for (int p = wid; p < npairs; p += nw) {
        int e0 = p << 5;
        // non-temporal: read-once streams must not evict dirty Hn lines
        int vd0 = __builtin_nontemporal_load(dstp + e0 + m);
        int vs0 = __builtin_nontemporal_load(srcp + e0 + m);
        int vd1 = __builtin_nontemporal_load(dstp + e0 + 16 + m);
        int vs1 = __builtin_nontemporal_load(srcp + e0 + 16 + m);
        half8 av0a = nt_load_h8(A  + (size_t)vd0 * 64 + q * 8);
        half8 av0b = nt_load_h8(A  + (size_t)vd0 * 64 + 32 + q * 8);
        half8 bv0a = nt_load_h8(Bm + (size_t)vs0 * 64 + q * 8);
        half8 bv0b = nt_load_h8(Bm + (size_t)vs0 * 64 + 32 + q * 8);
        half8 av1a = nt_load_h8(A  + (size_t)vd1 * 64 + q * 8);
        half8 av1b = nt_load_h8(A  + (size_t)vd1 * 64 + 32 + q * 8);
        half8 bv1a = nt_load_h8(Bm + (size_t)vs1 * 64 + q * 8);
        half8 bv1b = nt_load_h8(Bm + (size_t)vs1 * 64 + 32 + q * 8);

        half8 h0a = __builtin_elementwise_max(av0a + bv0a, zero8);
        half8 h0b = __builtin_elementwise_max(av0b + bv0b, zero8);
        half8 h1a = __builtin_elementwise_max(av1a + bv1a, zero8);
        half8 h1b = __builtin_elementwise_max(av1b + bv1b, zero8);

        floatx4 c00 = {0.f, 0.f, 0.f, 0.f}, c01 = {0.f, 0.f, 0.f, 0.f};
        floatx4 c10 = {0.f, 0.f, 0.f, 0.f}, c11 = {0.f, 0.f, 0.f, 0.f};
        c00 = __builtin_amdgcn_mfma_f32_16x16x32_f16(h0a, wf[0][0], c00, 0, 0, 0);
        c01 = __builtin_amdgcn_mfma_f32_16x16x32_f16(h0a, wf[0][1], c01, 0, 0, 0);
        c10 = __builtin_amdgcn_mfma_f32_16x16x32_f16(h1a, wf[0][0], c10, 0, 0, 0);
        c11 = __builtin_amdgcn_mfma_f32_16x16x32_f16(h1a, wf[0][1], c11, 0, 0, 0);
        c00 = __builtin_amdgcn_mfma_f32_16x16x32_f16(h0b, wf[1][0], c00, 0, 0, 0);
        c01 = __builtin_amdgcn_mfma_f32_16x16x32_f16(h0b, wf[1][1], c01, 0, 0, 0);
        c10 = __builtin_amdgcn_mfma_f32_16x16x32_f16(h1b, wf[1][0], c10, 0, 0, 0);
        c11 = __builtin_amdgcn_mfma_f32_16x16x32_f16(h1b, wf[1][1], c11, 0, 0, 0);

#pragma unroll
        for (int r = 0; r < 4; r++) {
            int m2 = (q << 2) + r;
            int dd0 = __shfl(vd0, m2, 64);
            int dd1 = __shfl(vd1, m2, 64);
            float o00 = fast_tanh(c00[r] + cb2a);
            float o01 = fast_tanh(c01[r] + cb2b);
            float o10 = fast_tanh(c10[r] + cb2a);
            float o11 = fast_tanh(c11[r] + cb2b);
            atomic_pk_add_f16(Hn + (size_t)dd0 * 32 + 2 * m, pk_h2(o00, o01));
            atomic_pk_add_f16(Hn + (size_t)dd1 * 32 + 2 * m, pk_h2(o10, o11));
        }
    }

    // tail: edges beyond the last full 32-pair (covers E%32)
    int tstart = npairs << 5;
    int tail = E - tstart;
    if (tail && wid == 0 && lane < tail) {
        int e = tstart + lane;
        int vd = dstp[e], vs = srcp[e];
        float h[64];
        for (int k = 0; k < 64; k++) {
            float a = h2f(A[(size_t)vd * 64 + k]);
            float b = h2f(Bm[(size_t)vs * 64 + k]);
            h[k] = fmaxf(a + b, 0.f);
        }
        for (int j = 0; j < 16; j++) {
            float acc0 = conv_b2[2 * j], acc1 = conv_b2[2 * j + 1];
            for (int k = 0; k < 64; k++) {
                acc0 += h[k] * conv_w2[k * 32 + 2 * j];
                acc1 += h[k] * conv_w2[k * 32 + 2 * j + 1];
            }
            atomic_pk_add_f16(Hn + (size_t)vd * 32 + 2 * j, pk_h2(fast_tanh(acc0), fast_tanh(acc1)));
        }
    }
}

// ---------------- K4: pool (128 nodes/block; nt Hn reads) ----------------
__global__ __launch_bounds__(256) void k_pool(const unsigned short* __restrict__ Hn,
                                              const int* __restrict__ batch,
                                              float* __restrict__ gacc, int N) {
    const int NPB = 128;
    int c = threadIdx.x & 31;
    int r = threadIdx.x >> 5;  // 0..7
    int n0 = blockIdx.x * NPB;
    int nend = min(n0 + NPB, N);
    int gcur = -1;
    float acc = 0.f;
    for (int n = n0 + r; n < nend; n += 8) {
        int g = batch[n];
        if (g != gcur) {
            if (gcur >= 0) unsafeAtomicAdd(&gacc[gcur * 46 + c], acc);
            gcur = g; acc = 0.f;
        }
        acc += h2f(__builtin_nontemporal_load(Hn + (size_t)n * 32 + c));
    }
    if (gcur >= 0) unsafeAtomicAdd(&gacc[gcur * 46 + c], acc);
}

// ---------------- K5: output MLP ----------------
__global__ void k_out(const float* __restrict__ gacc,
                      const float* __restrict__ out_w1, const float* __restrict__ out_b1,
                      const float* __restrict__ out_w2, const float* __restrict__ out_b2,
                      float* __restrict__ out, int G) {
    int g = blockIdx.x * blockDim.x + threadIdx.x;
    if (g >= G) return;
    float cnt = fmaxf(gacc[g * 46 + 45], 1.0f);
    float inv = 1.0f / cnt;
    float f[45];
#pragma unroll
    for (int i = 0; i < 45; i++) f[i] = gacc[g * 46 + i] * inv;
    float h[32];
#pragma unroll
    for (int j = 0; j < 32; j++) {
        float acc = out_b1[j];
#pragma unroll
        for (int k = 0; k < 45; k++) acc += f[k] * out_w1[k * 32 + j];
        h[j] = fmaxf(acc, 0.f);
    }
    float o = out_b2[0];
#pragma unroll
    for (int j = 0; j < 32; j++) o += h[j] * out_w2[j];
    out[g] = fast_sigmoid(o);
}

extern "C" void kernel_launch(void* const* d_in, const int* in_sizes, int n_in,
                              void* d_out, int out_size, void* d_ws, size_t ws_size,
                              hipStream_t stream) {
    const float* x      = (const float*)d_in[0];
    const int*   ei     = (const int*)d_in[1];
    const int*   batch  = (const int*)d_in[2];
    const float* bn_g   = (const float*)d_in[3];
    const float* bn_b   = (const float*)d_in[4];
    const float* in_w1  = (const float*)d_in[5];
    const float* in_b1  = (const float*)d_in[6];
    const float* in_w2  = (const float*)d_in[7];
    const float* in_b2  = (const float*)d_in[8];
    const float* cw1    = (const float*)d_in[9];
    const float* cb1    = (const float*)d_in[10];
    const float* cw2    = (const float*)d_in[11];
    const float* cb2    = (const float*)d_in[12];
    const float* ow1    = (const float*)d_in[13];
    const float* ob1    = (const float*)d_in[14];
    const float* ow2    = (const float*)d_in[15];
    const float* ob2    = (const float*)d_in[16];

    int N = in_sizes[0] / 13;
    int E = in_sizes[1] / 2;
    int G = out_size;
    int Npad = (N + 255) & ~255;

    auto al = [](size_t v) { return (v + 255) & ~(size_t)255; };
    char* ws = (char*)d_ws;
    size_t hn_off   = 0;                                  // Hn: f16 [N][32]
    size_t gacc_off = al((size_t)N * 32 * 2);
    size_t part_off = gacc_off + al((size_t)G * 46 * 4);
    size_t a_off    = part_off + al(2 * NBLK_STAT * 32 * 4);
    size_t b_off    = a_off + al((size_t)Npad * 64 * 2);
    size_t ft_off   = b_off + al((size_t)Npad * 64 * 2);
    size_t wc_off   = ft_off + al((size_t)Npad * 64 * 2);

    unsigned short* Hn   = (unsigned short*)(ws + hn_off);
    float* gacc          = (float*)(ws + gacc_off);
    float* part          = (float*)(ws + part_off);
    unsigned short* A    = (unsigned short*)(ws + a_off);
    unsigned short* Bm   = (unsigned short*)(ws + b_off);
    unsigned short* feat = (unsigned short*)(ws + ft_off);
    unsigned short* wcat = (unsigned short*)(ws + wc_off);

    int hnq = (N * 32 * 2) / 16;        // Hn size in uint4s (N*64 bytes)
    int gn  = G * 46;

    k_bnstat<<<NBLK_STAT, 256, 0, stream>>>(x, N, part, (uint4*)Hn, hnq, gacc, gn,
                                            cw1, wcat);
    k_nodeA<<<Npad / 256, 256, 0, stream>>>(x, batch, bn_g, bn_b,
                                            in_w1, in_b1, in_w2, in_b2,
                                            part, feat, gacc, N);
    k_nodeB<<<Npad / 64, 256, 0, stream>>>(feat, wcat, cb1, A, Bm, N);
    k_edge<<<2048, 256, 0, stream>>>(ei, A, Bm, cw2, cb2, Hn, E);
    k_pool<<<(N + 127) / 128, 256, 0, stream>>>(Hn, batch, gacc, N);
    k_out<<<1, 128, 0, stream>>>(gacc, ow1, ob1, ow2, ob2, (float*)d_out, G);
}

// Round 13
// 261.816 us; speedup vs baseline: 1.6360x; 1.0449x over previous
//
#include <hip/hip_runtime.h>

// EdgeNet: BN -> inputnet MLP -> EdgeConv(linearized) -> mean-pool -> output MLP
// N=50000, E=1.6M, D=13, H=32, G=128. All I/O float32.
// EdgeConv: per-node A = feat@(Wtop-Wbot)+b1, B = feat@Wbot (fp16);
// per-edge h = relu(A[dst]+B[src]); msg = tanh(h@W2+b2) via MFMA f16,
// scattered to Hn via packed f16 atomics.
// FINAL (R19 = exact R16, 260.6us verified):
//  - k_edge 89us = memory-side atomic roofline: 25.6M dword RMW / 89us =
//    288 G/s ~ 94% of TCC atomic-slot bound. Schedule-invariant (R11),
//    cache-invariant (R18: nt loads -> WRITE unchanged, FETCH up, dur +19us),
//    and every atomic-free formulation costs more (R12 sort +178us, R15
//    bucketing latency-starved, R17 LDS-atomic 275us, R13 coop 6x).
//  - non-edge kernels TLP-optimized (R16): nodeA MLP 196 blocks, nodeB dense
//    MFMA GEMM 784 blocks, pool 391 blocks.
//  - ~125us/iter is fixed harness reset overhead (dispatch-ID accounting).

typedef __attribute__((ext_vector_type(4))) float floatx4;
typedef __attribute__((ext_vector_type(8))) short short8;
typedef __attribute__((ext_vector_type(8))) _Float16 half8;
typedef __attribute__((ext_vector_type(2))) __fp16 fp16x2;

__device__ __forceinline__ unsigned short f2bf(float f) {
    unsigned int u = __float_as_uint(f);
    u += 0x7FFFu + ((u >> 16) & 1u);   // RTNE
    return (unsigned short)(u >> 16);
}
__device__ __forceinline__ unsigned short f2h(float f) {
    _Float16 h = (_Float16)f;
    return __builtin_bit_cast(unsigned short, h);
}
__device__ __forceinline__ float h2f(unsigned short u) {
    return (float)__builtin_bit_cast(_Float16, u);
}
__device__ __forceinline__ float fast_tanh(float x) {
    float ax = fminf(fabsf(x), 20.0f);
    float e = __expf(2.0f * ax);
    float r = 1.0f - 2.0f * __builtin_amdgcn_rcpf(e + 1.0f);
    return copysignf(r, x);
}
__device__ __forceinline__ float fast_sigmoid(float x) {
    float xc = fminf(fmaxf(x, -30.f), 30.f);
    return 1.0f / (1.0f + __expf(-xc));
}
__device__ __forceinline__ unsigned int pk_h2(float a, float b) {
    fp16x2 p = __builtin_amdgcn_cvt_pkrtz(a, b);
    return __builtin_bit_cast(unsigned int, p);
}
// fire-and-forget packed f16x2 atomic add (memory-side RMW)
__device__ __forceinline__ void atomic_pk_add_f16(unsigned short* addr, unsigned int packed) {
    asm volatile("global_atomic_pk_add_f16 %0, %1, off" :: "v"(addr), "v"(packed) : "memory");
}

#define NBLK_STAT 120

// ---- K1: BN partials + zero Hn/gacc + precompute WcatT (bf16 [128][64]) ----
__global__ __launch_bounds__(256) void k_bnstat(const float* __restrict__ x, int N,
                                                float* __restrict__ part,
                                                uint4* __restrict__ HnZ, int hnq,
                                                float* __restrict__ gacc, int gn,
                                                const float* __restrict__ conv_w1,
                                                unsigned short* __restrict__ wcat) {
    int tid = blockIdx.x * blockDim.x + threadIdx.x;
    int stride = gridDim.x * blockDim.x;
    uint4 z4 = make_uint4(0u, 0u, 0u, 0u);
    for (int i = tid; i < hnq; i += stride) HnZ[i] = z4;
    for (int i = tid; i < gn; i += stride) gacc[i] = 0.f;
    // WcatT[c][k], c=0..127 output col, k=0..63 input: top-bot | bot
    for (int i = tid; i < 128 * 64; i += stride) {
        int c = i >> 6, k = i & 63;
        float v = 0.f;
        if (k < 45) {
            int cc = c & 63;
            float bot = conv_w1[(45 + k) * 64 + cc];
            v = (c < 64) ? (conv_w1[k * 64 + cc] - bot) : bot;
        }
        wcat[i] = f2bf(v);
    }

    float s[13], q[13];
#pragma unroll
    for (int d = 0; d < 13; d++) { s[d] = 0.f; q[d] = 0.f; }
    for (int n = tid; n < N; n += stride) {
        const float* row = x + (size_t)n * 13;
#pragma unroll
        for (int d = 0; d < 13; d++) { float f = row[d]; s[d] += f; q[d] += f * f; }
    }
#pragma unroll
    for (int d = 0; d < 13; d++) {
        for (int off = 32; off > 0; off >>= 1) {
            s[d] += __shfl_down(s[d], off, 64);
            q[d] += __shfl_down(q[d], off, 64);
        }
    }
    __shared__ float red[4][26];
    int w = threadIdx.x >> 6;
    if ((threadIdx.x & 63) == 0) {
#pragma unroll
        for (int d = 0; d < 13; d++) { red[w][d] = s[d]; red[w][13 + d] = q[d]; }
    }
    __syncthreads();
    if (threadIdx.x < 26) {
        float v = red[0][threadIdx.x] + red[1][threadIdx.x] + red[2][threadIdx.x] + red[3][threadIdx.x];
        int d = threadIdx.x;
        if (d < 13) part[blockIdx.x * 32 + d] = v;
        else        part[NBLK_STAT * 32 + blockIdx.x * 32 + (d - 13)] = v;
    }
}

// ---------------- K2a: per-node MLP -> feat (bf16 [Npad][64]) ----------------
__global__ __launch_bounds__(256) void k_nodeA(
    const float* __restrict__ x, const int* __restrict__ batch,
    const float* __restrict__ bn_g, const float* __restrict__ bn_b,
    const float* __restrict__ in_w1, const float* __restrict__ in_b1,
    const float* __restrict__ in_w2, const float* __restrict__ in_b2,
    const float* __restrict__ part,
    unsigned short* __restrict__ feat, float* __restrict__ gacc, int N) {
    __shared__ float sW1[13 * 32], sB1[32], sW2[32 * 32], sB2[32];
    __shared__ float sScl[16], sShf[16];
    __shared__ float sRedS[13][8], sRedQ[13][8];
    __shared__ unsigned short sFeat[256 * 64];
    int tid = threadIdx.x;

    for (int i = tid; i < 13 * 32; i += 256) sW1[i] = in_w1[i];
    if (tid < 32) { sB1[tid] = in_b1[tid]; sB2[tid] = in_b2[tid]; }
    for (int i = tid; i < 32 * 32; i += 256) sW2[i] = in_w2[i];
    if (tid < 104) {
        int d = tid >> 3, j = tid & 7;
        float su = 0.f, sq = 0.f;
        for (int b = j; b < NBLK_STAT; b += 8) {
            su += part[b * 32 + d];
            sq += part[NBLK_STAT * 32 + b * 32 + d];
        }
        sRedS[d][j] = su; sRedQ[d][j] = sq;
    }
    __syncthreads();
    if (tid < 13) {
        float su = 0.f, sq = 0.f;
#pragma unroll
        for (int j = 0; j < 8; j++) { su += sRedS[tid][j]; sq += sRedQ[tid][j]; }
        float invN = 1.0f / (float)N;
        float mu = su * invN;
        float var = fmaxf(sq * invN - mu * mu, 0.f);
        float sc = bn_g[tid] / sqrtf(var + 1e-5f);
        sScl[tid] = sc;
        sShf[tid] = bn_b[tid] - mu * sc;
    }
    __syncthreads();

    int n = blockIdx.x * 256 + tid;
    bool valid = (n < N);
    int nl = valid ? n : (N - 1);

    float X[13];
#pragma unroll
    for (int d = 0; d < 13; d++)
        X[d] = x[(size_t)nl * 13 + d] * sScl[d] + sShf[d];
    float h1[32];
#pragma unroll
    for (int j = 0; j < 32; j++) {
        float acc = sB1[j];
#pragma unroll
        for (int d = 0; d < 13; d++) acc += X[d] * sW1[d * 32 + j];
        h1[j] = fmaxf(acc, 0.f);
    }
    float h2[32];
#pragma unroll
    for (int j = 0; j < 32; j++) {
        float acc = sB2[j];
#pragma unroll
        for (int k = 0; k < 32; k++) acc += h1[k] * sW2[k * 32 + j];
        h2[j] = fast_tanh(acc);
    }

    unsigned int fw[16];
#pragma unroll
    for (int i = 0; i < 16; i++) fw[i] = 0;
    unsigned int xw[7];
#pragma unroll
    for (int i = 0; i < 7; i++) xw[i] = 0;
    if (valid) {
#pragma unroll
        for (int i = 0; i < 16; i++)
            fw[i] = (unsigned)f2bf(h2[2 * i]) | ((unsigned)f2bf(h2[2 * i + 1]) << 16);
#pragma unroll
        for (int i = 0; i < 6; i++)
            xw[i] = (unsigned)f2bf(X[2 * i]) | ((unsigned)f2bf(X[2 * i + 1]) << 16);
        xw[6] = (unsigned)f2bf(X[12]);
    }
    {
        unsigned short* row = sFeat + tid * 64;
        ((uint4*)row)[0] = make_uint4(fw[0], fw[1], fw[2], fw[3]);
        ((uint4*)row)[1] = make_uint4(fw[4], fw[5], fw[6], fw[7]);
        ((uint4*)row)[2] = make_uint4(fw[8], fw[9], fw[10], fw[11]);
        ((uint4*)row)[3] = make_uint4(fw[12], fw[13], fw[14], fw[15]);
        ((uint4*)row)[4] = make_uint4(xw[0], xw[1], xw[2], xw[3]);
        ((uint4*)row)[5] = make_uint4(xw[4], xw[5], xw[6], 0u);
        ((uint4*)row)[6] = make_uint4(0u, 0u, 0u, 0u);
        ((uint4*)row)[7] = make_uint4(0u, 0u, 0u, 0u);
    }

    {
        int g = valid ? batch[n] : -1;
        unsigned long long uni = __ballot(g == __shfl(g, 0, 64));
        if (uni == ~0ull && g >= 0) {
            float red[14];
#pragma unroll
            for (int d = 0; d < 13; d++) red[d] = X[d];
            red[13] = 1.0f;
#pragma unroll
            for (int d = 0; d < 14; d++)
                for (int off = 32; off > 0; off >>= 1)
                    red[d] += __shfl_down(red[d], off, 64);
            if ((tid & 63) == 0) {
#pragma unroll
                for (int d = 0; d < 13; d++) unsafeAtomicAdd(&gacc[g * 46 + 32 + d], red[d]);
                unsafeAtomicAdd(&gacc[g * 46 + 45], red[13]);
            }
        } else if (valid) {
#pragma unroll
            for (int d = 0; d < 13; d++) unsafeAtomicAdd(&gacc[g * 46 + 32 + d], X[d]);
            unsafeAtomicAdd(&gacc[g * 46 + 45], 1.0f);
        }
    }
    __syncthreads();

    // coalesced linear copy: 256*64 ushorts = 2048 uint4
    uint4* dst = (uint4*)(feat + (size_t)blockIdx.x * 256 * 64);
    const uint4* srcq = (const uint4*)sFeat;
#pragma unroll
    for (int j = 0; j < 8; j++) dst[tid + j * 256] = srcq[tid + j * 256];
}

// ---------------- K2b: dense GEMM feat@WcatT -> A|Bm (fp16) ----------------
__global__ __launch_bounds__(256) void k_nodeB(
    const unsigned short* __restrict__ feat, const unsigned short* __restrict__ wcat,
    const float* __restrict__ conv_b1,
    unsigned short* __restrict__ A, unsigned short* __restrict__ Bm, int N) {
    int tid = threadIdx.x;
    int lane = tid & 63;
    int w = tid >> 6;
    int q = lane >> 4;
    int m = lane & 15;

    short8 wf[2][8];
#pragma unroll
    for (int ks = 0; ks < 2; ks++)
#pragma unroll
        for (int t = 0; t < 8; t++)
            wf[ks][t] = *(const short8*)(wcat + (t * 16 + m) * 64 + ks * 32 + q * 8);
    float cb1v[4];
#pragma unroll
    for (int t = 0; t < 4; t++) cb1v[t] = conv_b1[t * 16 + m];

    int row0 = blockIdx.x * 64 + w * 16;
    const unsigned short* ar = feat + (size_t)(row0 + m) * 64;
    short8 a0 = *(const short8*)(ar + q * 8);
    short8 a1 = *(const short8*)(ar + 32 + q * 8);
    floatx4 c[8];
#pragma unroll
    for (int t = 0; t < 8; t++) {
        floatx4 z = {0.f, 0.f, 0.f, 0.f};
        c[t] = __builtin_amdgcn_mfma_f32_16x16x32_bf16(a0, wf[0][t], z, 0, 0, 0);
        c[t] = __builtin_amdgcn_mfma_f32_16x16x32_bf16(a1, wf[1][t], c[t], 0, 0, 0);
    }
#pragma unroll
    for (int r = 0; r < 4; r++) {
        int row = row0 + (q << 2) + r;
        if (row < N) {
#pragma unroll
            for (int t = 0; t < 4; t++)
                A[(size_t)row * 64 + t * 16 + m] = f2h(c[t][r] + cb1v[t]);
#pragma unroll
            for (int t = 4; t < 8; t++)
                Bm[(size_t)row * 64 + (t - 4) * 16 + m] = f2h(c[t][r]);
        }
    }
}

// ---------------- K3: edge phase (fp16 packed math + MFMA f16) ----------------
__global__ __launch_bounds__(256) void k_edge(
    const int* __restrict__ ei,
    const unsigned short* __restrict__ A, const unsigned short* __restrict__ Bm,
    const float* __restrict__ conv_w2, const float* __restrict__ conv_b2,
    unsigned short* __restrict__ Hn, int E) {
    int lane = threadIdx.x & 63;
    int wid  = blockIdx.x * (blockDim.x >> 6) + (threadIdx.x >> 6);
    int nw   = gridDim.x * (blockDim.x >> 6);
    int q = lane >> 4;
    int m = lane & 15;

    half8 wf[2][2];
#pragma unroll
    for (int s = 0; s < 2; s++)
#pragma unroll
        for (int t = 0; t < 2; t++)
#pragma unroll
            for (int j = 0; j < 8; j++)
                wf[s][t][j] = (_Float16)conv_w2[(s * 32 + q * 8 + j) * 32 + 2 * m + t];
    float cb2a = conv_b2[2 * m];
    float cb2b = conv_b2[2 * m + 1];

    const int* srcp = ei;
    const int* dstp = ei + E;
    int npairs = E >> 5;

    const half8 zero8 = (half8)(_Float16)0.0f;

    for (int p = wid; p < npairs; p += nw) {
        int e0 = p << 5;
        int vd0 = dstp[e0 + m];
        int vs0 = srcp[e0 + m];
        int vd1 = dstp[e0 + 16 + m];
        int vs1 = srcp[e0 + 16 + m];
        uint4 av0a = *(const uint4*)(A  + (size_t)vd0 * 64 + q * 8);
        uint4 av0b = *(const uint4*)(A  + (size_t)vd0 * 64 + 32 + q * 8);
        uint4 bv0a = *(const uint4*)(Bm + (size_t)vs0 * 64 + q * 8);
        uint4 bv0b = *(const uint4*)(Bm + (size_t)vs0 * 64 + 32 + q * 8);
        uint4 av1a = *(const uint4*)(A  + (size_t)vd1 * 64 + q * 8);
        uint4 av1b = *(const uint4*)(A  + (size_t)vd1 * 64 + 32 + q * 8);
        uint4 bv1a = *(const uint4*)(Bm + (size_t)vs1 * 64 + q * 8);
        uint4 bv1b = *(const uint4*)(Bm + (size_t)vs1 * 64 + 32 + q * 8);

        auto mk = [&zero8](uint4 av, uint4 bv) -> half8 {
            half8 a = __builtin_bit_cast(half8, av);
            half8 b = __builtin_bit_cast(half8, bv);
            half8 s = a + b;
            return __builtin_elementwise_max(s, zero8);
        };
        half8 h0a = mk(av0a, bv0a);
        half8 h0b = mk(av0b, bv0b);
        half8 h1a = mk(av1a, bv1a);
        half8 h1b = mk(av1b, bv1b);

        floatx4 c00 = {0.f, 0.f, 0.f, 0.f}, c01 = {0.f, 0.f, 0.f, 0.f};
        floatx4 c10 = {0.f, 0.f, 0.f, 0.f}, c11 = {0.f, 0.f, 0.f, 0.f};
        c00 = __builtin_amdgcn_mfma_f32_16x16x32_f16(h0a, wf[0][0], c00, 0, 0, 0);
        c01 = __builtin_amdgcn_mfma_f32_16x16x32_f16(h0a, wf[0][1], c01, 0, 0, 0);
        c10 = __builtin_amdgcn_mfma_f32_16x16x32_f16(h1a, wf[0][0], c10, 0, 0, 0);
        c11 = __builtin_amdgcn_mfma_f32_16x16x32_f16(h1a, wf[0][1], c11, 0, 0, 0);
        c00 = __builtin_amdgcn_mfma_f32_16x16x32_f16(h0b, wf[1][0], c00, 0, 0, 0);
        c01 = __builtin_amdgcn_mfma_f32_16x16x32_f16(h0b, wf[1][1], c01, 0, 0, 0);
        c10 = __builtin_amdgcn_mfma_f32_16x16x32_f16(h1b, wf[1][0], c10, 0, 0, 0);
        c11 = __builtin_amdgcn_mfma_f32_16x16x32_f16(h1b, wf[1][1], c11, 0, 0, 0);

#pragma unroll
        for (int r = 0; r < 4; r++) {
            int m2 = (q << 2) + r;
            int dd0 = __shfl(vd0, m2, 64);
            int dd1 = __shfl(vd1, m2, 64);
            float o00 = fast_tanh(c00[r] + cb2a);
            float o01 = fast_tanh(c01[r] + cb2b);
            float o10 = fast_tanh(c10[r] + cb2a);
            float o11 = fast_tanh(c11[r] + cb2b);
            atomic_pk_add_f16(Hn + (size_t)dd0 * 32 + 2 * m, pk_h2(o00, o01));
            atomic_pk_add_f16(Hn + (size_t)dd1 * 32 + 2 * m, pk_h2(o10, o11));
        }
    }

    // tail: edges beyond the last full 32-pair (covers E%32)
    int tstart = npairs << 5;
    int tail = E - tstart;
    if (tail && wid == 0 && lane < tail) {
        int e = tstart + lane;
        int vd = dstp[e], vs = srcp[e];
        float h[64];
        for (int k = 0; k < 64; k++) {
            float a = h2f(A[(size_t)vd * 64 + k]);
            float b = h2f(Bm[(size_t)vs * 64 + k]);
            h[k] = fmaxf(a + b, 0.f);
        }
        for (int j = 0; j < 16; j++) {
            float acc0 = conv_b2[2 * j], acc1 = conv_b2[2 * j + 1];
            for (int k = 0; k < 64; k++) {
                acc0 += h[k] * conv_w2[k * 32 + 2 * j];
                acc1 += h[k] * conv_w2[k * 32 + 2 * j + 1];
            }
            atomic_pk_add_f16(Hn + (size_t)vd * 32 + 2 * j, pk_h2(fast_tanh(acc0), fast_tanh(acc1)));
        }
    }
}

// ---------------- K4: pool (128 nodes/block -> 391 blocks) ----------------
__global__ __launch_bounds__(256) void k_pool(const unsigned short* __restrict__ Hn,
                                              const int* __restrict__ batch,
                                              float* __restrict__ gacc, int N) {
    const int NPB = 128;
    int c = threadIdx.x & 31;
    int r = threadIdx.x >> 5;  // 0..7
    int n0 = blockIdx.x * NPB;
    int nend = min(n0 + NPB, N);
    int gcur = -1;
    float acc = 0.f;
    for (int n = n0 + r; n < nend; n += 8) {
        int g = batch[n];
        if (g != gcur) {
            if (gcur >= 0) unsafeAtomicAdd(&gacc[gcur * 46 + c], acc);
            gcur = g; acc = 0.f;
        }
        acc += h2f(Hn[(size_t)n * 32 + c]);
    }
    if (gcur >= 0) unsafeAtomicAdd(&gacc[gcur * 46 + c], acc);
}

// ---------------- K5: output MLP ----------------
__global__ void k_out(const float* __restrict__ gacc,
                      const float* __restrict__ out_w1, const float* __restrict__ out_b1,
                      const float* __restrict__ out_w2, const float* __restrict__ out_b2,
                      float* __restrict__ out, int G) {
    int g = blockIdx.x * blockDim.x + threadIdx.x;
    if (g >= G) return;
    float cnt = fmaxf(gacc[g * 46 + 45], 1.0f);
    float inv = 1.0f / cnt;
    float f[45];
#pragma unroll
    for (int i = 0; i < 45; i++) f[i] = gacc[g * 46 + i] * inv;
    float h[32];
#pragma unroll
    for (int j = 0; j < 32; j++) {
        float acc = out_b1[j];
#pragma unroll
        for (int k = 0; k < 45; k++) acc += f[k] * out_w1[k * 32 + j];
        h[j] = fmaxf(acc, 0.f);
    }
    float o = out_b2[0];
#pragma unroll
    for (int j = 0; j < 32; j++) o += h[j] * out_w2[j];
    out[g] = fast_sigmoid(o);
}

extern "C" void kernel_launch(void* const* d_in, const int* in_sizes, int n_in,
                              void* d_out, int out_size, void* d_ws, size_t ws_size,
                              hipStream_t stream) {
    const float* x      = (const float*)d_in[0];
    const int*   ei     = (const int*)d_in[1];
    const int*   batch  = (const int*)d_in[2];
    const float* bn_g   = (const float*)d_in[3];
    const float* bn_b   = (const float*)d_in[4];
    const float* in_w1  = (const float*)d_in[5];
    const float* in_b1  = (const float*)d_in[6];
    const float* in_w2  = (const float*)d_in[7];
    const float* in_b2  = (const float*)d_in[8];
    const float* cw1    = (const float*)d_in[9];
    const float* cb1    = (const float*)d_in[10];
    const float* cw2    = (const float*)d_in[11];
    const float* cb2    = (const float*)d_in[12];
    const float* ow1    = (const float*)d_in[13];
    const float* ob1    = (const float*)d_in[14];
    const float* ow2    = (const float*)d_in[15];
    const float* ob2    = (const float*)d_in[16];

    int N = in_sizes[0] / 13;
    int E = in_sizes[1] / 2;
    int G = out_size;
    int Npad = (N + 255) & ~255;

    auto al = [](size_t v) { return (v + 255) & ~(size_t)255; };
    char* ws = (char*)d_ws;
    size_t hn_off   = 0;                                  // Hn: f16 [N][32]
    size_t gacc_off = al((size_t)N * 32 * 2);
    size_t part_off = gacc_off + al((size_t)G * 46 * 4);
    size_t a_off    = part_off + al(2 * NBLK_STAT * 32 * 4);
    size_t b_off    = a_off + al((size_t)Npad * 64 * 2);
    size_t ft_off   = b_off + al((size_t)Npad * 64 * 2);
    size_t wc_off   = ft_off + al((size_t)Npad * 64 * 2);

    unsigned short* Hn   = (unsigned short*)(ws + hn_off);
    float* gacc          = (float*)(ws + gacc_off);
    float* part          = (float*)(ws + part_off);
    unsigned short* A    = (unsigned short*)(ws + a_off);
    unsigned short* Bm   = (unsigned short*)(ws + b_off);
    unsigned short* feat = (unsigned short*)(ws + ft_off);
    unsigned short* wcat = (unsigned short*)(ws + wc_off);

    int hnq = (N * 32 * 2) / 16;        // Hn size in uint4s (N*64 bytes)
    int gn  = G * 46;

    k_bnstat<<<NBLK_STAT, 256, 0, stream>>>(x, N, part, (uint4*)Hn, hnq, gacc, gn,
                                            cw1, wcat);
    k_nodeA<<<Npad / 256, 256, 0, stream>>>(x, batch, bn_g, bn_b,
                                            in_w1, in_b1, in_w2, in_b2,
                                            part, feat, gacc, N);
    k_nodeB<<<Npad / 64, 256, 0, stream>>>(feat, wcat, cb1, A, Bm, N);
    k_edge<<<2048, 256, 0, stream>>>(ei, A, Bm, cw2, cb2, Hn, E);
    k_pool<<<(N + 127) / 128, 256, 0, stream>>>(Hn, batch, gacc, N);
    k_out<<<1, 128, 0, stream>>>(gacc, ow1, ob1, ow2, ob2, (float*)d_out, G);
}